// Round 1
// baseline (329.113 us; speedup 1.0000x reference)
//
#include <hip/hip_runtime.h>

typedef __attribute__((ext_vector_type(4))) float floatx4;
typedef __attribute__((ext_vector_type(8))) short short8;

__device__ __forceinline__ unsigned short f2bf(float f) {
    union { float f; unsigned int i; } v; v.f = f;
    unsigned int x = v.i;
    unsigned int r = (x + 0x7FFFu + ((x >> 16) & 1u)) >> 16;   // RNE
    return (unsigned short)r;
}
__device__ __forceinline__ float bf2f(unsigned short u) {
    union { unsigned int i; float f; } v; v.i = ((unsigned int)u) << 16;
    return v.f;
}

// packed f32x2 -> bf16x2 (RNE), hw convert: low16 = cvt(lo), high16 = cvt(hi)
__device__ __forceinline__ unsigned int cvtpk_bf16(float lo, float hi) {
    unsigned int r;
    asm("v_cvt_pk_bf16_f32 %0, %1, %2" : "=v"(r) : "v"(lo), "v"(hi));
    return r;
}

// DPP lane-permute add helper (VALU-latency cross-lane, no LDS pipe).
// ctrl: 0x00-0xFF quad_perm, 0x120+N row_ror:N (within 16-lane rows).
template<int CTRL>
__device__ __forceinline__ float dppf(float x) {
    return __int_as_float(__builtin_amdgcn_update_dpp(
        0, __float_as_int(x), CTRL, 0xF, 0xF, false));
}

// ---------------- prep: rearrange phi (1024x24) and W (256x256) into bf16
// MFMA B-fragment order in workspace.
// phiF: [kstep 0..31][ntile 0..1][lane 0..63][j 0..7]  (32768 bf16 = 64KB)
// WF  : [ntile 0..15][kstep 0..7][lane 0..63][j 0..7]  (65536 bf16 = 128KB)
// B-fragment: lane holds B[k = (lane>>4)*8 + j][n = lane&15]; B[k][n] = W[n][k] / phi[k][n]
__global__ void mhc_prep(const float* __restrict__ phi, const float* __restrict__ W,
                         unsigned short* __restrict__ phiF, unsigned short* __restrict__ WF) {
    int e = blockIdx.x * 256 + threadIdx.x;
    if (e < 32768) {
        int j = e & 7, lane = (e >> 3) & 63, nt = (e >> 9) & 1, ks = e >> 10;
        int n = nt * 16 + (lane & 15);
        int k = ks * 32 + ((lane >> 4) & 3) * 8 + j;
        float v = (n < 24) ? phi[k * 24 + n] : 0.0f;
        phiF[e] = f2bf(v);
    } else {
        int e2 = e - 32768;
        int j = e2 & 7, lane = (e2 >> 3) & 63, ks = (e2 >> 9) & 7, nt = e2 >> 12;
        int n = nt * 16 + (lane & 15);
        int k = ks * 32 + ((lane >> 4) & 3) * 8 + j;
        WF[e2] = f2bf(W[n * 256 + k]);
    }
}

// ---------------- main fused kernel: 16 tokens per tile, grid-stride with
// register prefetch of the next tile (T14) so the HBM read stream overlaps
// the barrier-serialized compute phases.
#define XS_STRIDE 1032   // 1024 + 8 bf16 pad (2064B = 129*16: 16B aligned, banks spread)
#define XIN_STRIDE 264   // 256 + 8 bf16 pad (528B = 33*16)
#define CO_STRIDE 28     // floats, 112B (16B aligned)
#define NTILES 2048      // 8*4096 tokens / 16 per tile

__global__ __launch_bounds__(256, 3) void mhc_main(
    const float* __restrict__ x, const float* __restrict__ bias,
    const float* __restrict__ s_ap, const float* __restrict__ s_apo,
    const float* __restrict__ s_ar,
    const unsigned short* __restrict__ phiF, const unsigned short* __restrict__ WF,
    float* __restrict__ out)
{
    __shared__ unsigned short xs[16 * XS_STRIDE];   // x tile, bf16
    __shared__ unsigned short xin[16 * XIN_STRIDE]; // x_in tile, bf16
    __shared__ float lg[16 * CO_STRIDE];            // logits
    __shared__ float coef[16 * CO_STRIDE];          // [hpre0..3, hpost0..3, P[16]]

    const int t = threadIdx.x;
    const int lane = t & 63;
    const int w = t >> 6;
    const int quad = lane >> 4;
    const int col = lane & 15;

    int tile = blockIdx.x;            // gridDim.x = 768 < NTILES, always valid
    float4 pre[16];                   // prefetch registers: next tile's x
    {
        const float4* xg = (const float4*)(x) + (long)tile * 4096;
        #pragma unroll
        for (int ii = 0; ii < 16; ++ii) pre[ii] = xg[ii * 256 + t];
    }

    for (;;) {
        // ---- phase 0: regs -> bf16 LDS (tok = ii, elem offset = 4t) ----
        #pragma unroll
        for (int ii = 0; ii < 16; ++ii) {
            uint2 pk;
            pk.x = cvtpk_bf16(pre[ii].x, pre[ii].y);
            pk.y = cvtpk_bf16(pre[ii].z, pre[ii].w);
            *reinterpret_cast<uint2*>(&xs[ii * XS_STRIDE + t * 4]) = pk;
        }
        // issue next tile's loads NOW: they complete under phases 1-5
        const int next = tile + (int)gridDim.x;
        const bool has_next = (next < NTILES);
        if (has_next) {
            const float4* xg = (const float4*)(x) + (long)next * 4096;
            #pragma unroll
            for (int ii = 0; ii < 16; ++ii) pre[ii] = xg[ii * 256 + t];
        }
        __syncthreads();

        // ---- phase 1: logits = V(16x1024) @ phi(1024x24), waves 0,1 ----
        if (w < 2) {
            floatx4 acc = {0.0f, 0.0f, 0.0f, 0.0f};
            for (int ks = 0; ks < 32; ++ks) {
                short8 a = *reinterpret_cast<const short8*>(&xs[col * XS_STRIDE + ks * 32 + quad * 8]);
                short8 b = *reinterpret_cast<const short8*>(&phiF[(ks * 2 + w) * 512 + lane * 8]);
                acc = __builtin_amdgcn_mfma_f32_16x16x32_bf16(a, b, acc, 0, 0, 0);
            }
            int n = w * 16 + col;
            if (n < 24) {
                #pragma unroll
                for (int r = 0; r < 4; ++r)
                    lg[(quad * 4 + r) * CO_STRIDE + n] = acc[r];
            }
        }
        __syncthreads();

        // ---- phase 2: rms-norm, sigmoids, Sinkhorn (16 lanes/token, DPP) ----
        {
            int g = t >> 4, p = t & 15;
            float a = lg[g * CO_STRIDE + p];
            float b2 = (p < 8) ? lg[g * CO_STRIDE + 16 + p] : 0.0f;
            float s = a * a + b2 * b2;
            // 16-lane allreduce via row rotations (VALU latency, no LDS pipe)
            s += dppf<0x121>(s);   // row_ror:1
            s += dppf<0x122>(s);   // row_ror:2
            s += dppf<0x124>(s);   // row_ror:4
            s += dppf<0x128>(s);   // row_ror:8
            float rinv = 1.0f / sqrtf(s * (1.0f / 24.0f) + 1e-6f);
            float yP = lg[g * CO_STRIDE + 8 + p] * rinv + bias[8 + p];
            float P = expf(s_ar[0] * yP);
            for (int it = 0; it < 20; ++it) {
                // row sum (axis -1): full-quad sum via quad rotations
                float r = P + dppf<0x39>(P);      // quad_perm [1,2,3,0]
                r += dppf<0x4E>(r);               // quad_perm [2,3,0,1]
                P *= __builtin_amdgcn_rcpf(r + 1e-6f);
                // col sum (axis -2): lanes p, p+4, p+8, p+12
                float c = P + dppf<0x124>(P);     // row_ror:4
                c += dppf<0x128>(c);              // row_ror:8
                P *= __builtin_amdgcn_rcpf(c + 1e-6f);
            }
            coef[g * CO_STRIDE + 8 + p] = P;
            if (p < 8) {
                float yh = a * rinv + bias[p];
                float h = (p < 4) ? 1.0f / (1.0f + expf(-s_ap[0] * yh))
                                  : 2.0f / (1.0f + expf(-s_apo[0] * yh));
                coef[g * CO_STRIDE + p] = h;
            }
        }
        __syncthreads();

        // ---- phase 3: x_in[tok][c] = sum_i hpre[i] * x[tok][i][c], c = t ----
        {
            int c = t;
            #pragma unroll 4
            for (int tok = 0; tok < 16; ++tok) {
                float4 h4 = *reinterpret_cast<const float4*>(&coef[tok * CO_STRIDE]);
                const unsigned short* xr = &xs[tok * XS_STRIDE + c];
                float s = h4.x * bf2f(xr[0]) + h4.y * bf2f(xr[256])
                        + h4.z * bf2f(xr[512]) + h4.w * bf2f(xr[768]);
                xin[tok * XIN_STRIDE + c] = f2bf(s);
            }
        }
        __syncthreads();

        // ---- phase 4: f_out = Xin(16x256) @ W^T, wave w does ntiles 4w..4w+3 ----
        short8 afr[8];
        #pragma unroll
        for (int ks = 0; ks < 8; ++ks)
            afr[ks] = *reinterpret_cast<const short8*>(&xin[col * XIN_STRIDE + ks * 32 + quad * 8]);
        floatx4 accs[4];
        #pragma unroll
        for (int nt = 0; nt < 4; ++nt) {
            floatx4 acc = {0.0f, 0.0f, 0.0f, 0.0f};
            int ntile = w * 4 + nt;
            #pragma unroll
            for (int ks = 0; ks < 8; ++ks) {
                short8 b = *reinterpret_cast<const short8*>(&WF[(ntile * 8 + ks) * 512 + lane * 8]);
                acc = __builtin_amdgcn_mfma_f32_16x16x32_bf16(afr[ks], b, acc, 0, 0, 0);
            }
            accs[nt] = acc;
        }

        // ---- phase 5: out[tok][o][c] = sum_i P[o][i] x[tok][i][c] + hpost[o]*f ----
        const long base = (long)tile * 16384;
        #pragma unroll
        for (int r = 0; r < 4; ++r) {
            int tok = quad * 4 + r;
            const float* cb = &coef[tok * CO_STRIDE];
            float4 hpo = *reinterpret_cast<const float4*>(cb + 4);
            float4 P0  = *reinterpret_cast<const float4*>(cb + 8);
            float4 P1  = *reinterpret_cast<const float4*>(cb + 12);
            float4 P2  = *reinterpret_cast<const float4*>(cb + 16);
            float4 P3  = *reinterpret_cast<const float4*>(cb + 20);
            long ob = base + (long)tok * 1024;
            #pragma unroll
            for (int nt = 0; nt < 4; ++nt) {
                int c = (w * 4 + nt) * 16 + col;
                float f = accs[nt][r];
                const unsigned short* xr = &xs[tok * XS_STRIDE + c];
                float x0 = bf2f(xr[0]),   x1 = bf2f(xr[256]);
                float x2 = bf2f(xr[512]), x3 = bf2f(xr[768]);
                out[ob + c]       = P0.x * x0 + P0.y * x1 + P0.z * x2 + P0.w * x3 + hpo.x * f;
                out[ob + 256 + c] = P1.x * x0 + P1.y * x1 + P1.z * x2 + P1.w * x3 + hpo.y * f;
                out[ob + 512 + c] = P2.x * x0 + P2.y * x1 + P2.z * x2 + P2.w * x3 + hpo.z * f;
                out[ob + 768 + c] = P3.x * x0 + P3.y * x1 + P3.z * x2 + P3.w * x3 + hpo.w * f;
            }
        }

        tile = next;
        if (!has_next) break;
        __syncthreads();   // protect xs/coef before next tile's staging
    }
}

extern "C" void kernel_launch(void* const* d_in, const int* in_sizes, int n_in,
                              void* d_out, int out_size, void* d_ws, size_t ws_size,
                              hipStream_t stream) {
    const float* x    = (const float*)d_in[0];
    const float* phi  = (const float*)d_in[1];
    const float* bias = (const float*)d_in[2];
    const float* ap   = (const float*)d_in[3];
    const float* apo  = (const float*)d_in[4];
    const float* ar   = (const float*)d_in[5];
    const float* W    = (const float*)d_in[6];
    float* out = (float*)d_out;

    unsigned short* phiF = (unsigned short*)d_ws;           // 32768 bf16
    unsigned short* WF   = (unsigned short*)d_ws + 32768;   // 65536 bf16

    mhc_prep<<<384, 256, 0, stream>>>(phi, W, phiF, WF);
    // 768 blocks = 3 resident/CU (LDS 45KB, VGPR capped via launch_bounds);
    // each grid-strides 2-3 tiles so the prefetch pipeline stays primed.
    mhc_main<<<768, 256, 0, stream>>>(x, bias, ap, apo, ar, phiF, WF, out);
}

// Round 2
// 284.242 us; speedup vs baseline: 1.1579x; 1.1579x over previous
//
#include <hip/hip_runtime.h>

typedef __attribute__((ext_vector_type(4))) float floatx4;
typedef __attribute__((ext_vector_type(8))) short short8;

__device__ __forceinline__ unsigned short f2bf(float f) {
    union { float f; unsigned int i; } v; v.f = f;
    unsigned int x = v.i;
    unsigned int r = (x + 0x7FFFu + ((x >> 16) & 1u)) >> 16;   // RNE
    return (unsigned short)r;
}
__device__ __forceinline__ float bf2f(unsigned short u) {
    union { unsigned int i; float f; } v; v.i = ((unsigned int)u) << 16;
    return v.f;
}

// packed f32x2 -> bf16x2 (RNE), hw convert: low16 = cvt(lo), high16 = cvt(hi)
__device__ __forceinline__ unsigned int cvtpk_bf16(float lo, float hi) {
    unsigned int r;
    asm("v_cvt_pk_bf16_f32 %0, %1, %2" : "=v"(r) : "v"(lo), "v"(hi));
    return r;
}

// DPP lane-permute helper (VALU-latency cross-lane, no LDS pipe).
// ctrl: 0x00-0xFF quad_perm, 0x120+N row_ror:N (within 16-lane rows).
template<int CTRL>
__device__ __forceinline__ float dppf(float x) {
    return __int_as_float(__builtin_amdgcn_update_dpp(
        0, __float_as_int(x), CTRL, 0xF, 0xF, false));
}

// ---------------- prep: rearrange phi (1024x24) and W (256x256) into bf16
// MFMA B-fragment order in workspace.
// phiF: [kstep 0..31][ntile 0..1][lane 0..63][j 0..7]  (32768 bf16 = 64KB)
// WF  : [ntile 0..15][kstep 0..7][lane 0..63][j 0..7]  (65536 bf16 = 128KB)
// B-fragment: lane holds B[k = (lane>>4)*8 + j][n = lane&15]; B[k][n] = W[n][k] / phi[k][n]
__global__ void mhc_prep(const float* __restrict__ phi, const float* __restrict__ W,
                         unsigned short* __restrict__ phiF, unsigned short* __restrict__ WF) {
    int e = blockIdx.x * 256 + threadIdx.x;
    if (e < 32768) {
        int j = e & 7, lane = (e >> 3) & 63, nt = (e >> 9) & 1, ks = e >> 10;
        int n = nt * 16 + (lane & 15);
        int k = ks * 32 + ((lane >> 4) & 3) * 8 + j;
        float v = (n < 24) ? phi[k * 24 + n] : 0.0f;
        phiF[e] = f2bf(v);
    } else {
        int e2 = e - 32768;
        int j = e2 & 7, lane = (e2 >> 3) & 63, ks = (e2 >> 9) & 7, nt = e2 >> 12;
        int n = nt * 16 + (lane & 15);
        int k = ks * 32 + ((lane >> 4) & 3) * 8 + j;
        WF[e2] = f2bf(W[n * 256 + k]);
    }
}

// ================= kernel 1: coefficients =================
// 16 tokens/block. Stage x -> bf16 LDS, logits MFMA (all 4 waves, split-K),
// RMS + sigmoids + Sinkhorn (DPP, VALU-only), write 24 floats/token to cbuf.
// LDS = 33KB(xs) + 3.5KB(lgp) = 36.6KB -> 4 blocks/CU.
#define XS_STRIDE 1032   // 1024 + 8 bf16 pad (2064B = 129*16: 16B aligned, banks spread)
#define CO_STRIDE 28     // floats

__global__ __launch_bounds__(256) void mhc_coef(
    const float* __restrict__ x, const float* __restrict__ bias,
    const float* __restrict__ s_ap, const float* __restrict__ s_apo,
    const float* __restrict__ s_ar,
    const unsigned short* __restrict__ phiF,
    float* __restrict__ cbuf)
{
    __shared__ unsigned short xs[16 * XS_STRIDE];      // x tile, bf16
    __shared__ float lgp[2][16 * CO_STRIDE];           // logit partials (split-K)

    const int t = threadIdx.x;
    const int lane = t & 63;
    const int w = t >> 6;
    const int quad = lane >> 4;
    const int col = lane & 15;
    const long base = (long)blockIdx.x * (16 * 1024);

    // ---- phase 0: global fp32 -> bf16 LDS ----
    {
        const float4* xg = (const float4*)(x + base);
        #pragma unroll
        for (int ii = 0; ii < 16; ++ii) {
            int lin = ii * 256 + t;
            float4 v = xg[lin];
            int tok = lin >> 8;
            int k = (lin & 255) * 4;
            uint2 pk;
            pk.x = cvtpk_bf16(v.x, v.y);
            pk.y = cvtpk_bf16(v.z, v.w);
            *reinterpret_cast<uint2*>(&xs[tok * XS_STRIDE + k]) = pk;
        }
    }
    __syncthreads();

    // ---- phase 1: logits = V(16x1024) @ phi(1024x24), split-K over 4 waves ----
    // wave w: ntile = w&1, k-half = w>>1 (16 of 32 k-steps each)
    {
        floatx4 acc = {0.0f, 0.0f, 0.0f, 0.0f};
        const int ntile = w & 1;
        const int kh = w >> 1;
        for (int ks = kh * 16; ks < kh * 16 + 16; ++ks) {
            short8 a = *reinterpret_cast<const short8*>(&xs[col * XS_STRIDE + ks * 32 + quad * 8]);
            short8 b = *reinterpret_cast<const short8*>(&phiF[(ks * 2 + ntile) * 512 + lane * 8]);
            acc = __builtin_amdgcn_mfma_f32_16x16x32_bf16(a, b, acc, 0, 0, 0);
        }
        int n = ntile * 16 + col;
        if (n < 24) {
            #pragma unroll
            for (int r = 0; r < 4; ++r)
                lgp[kh][(quad * 4 + r) * CO_STRIDE + n] = acc[r];
        }
    }
    __syncthreads();

    // ---- phase 2: rms-norm, sigmoids, Sinkhorn (16 lanes/token, DPP) ----
    {
        int g = t >> 4, p = t & 15;
        float a  = lgp[0][g * CO_STRIDE + p]      + lgp[1][g * CO_STRIDE + p];
        float b2 = (p < 8) ? (lgp[0][g * CO_STRIDE + 16 + p] + lgp[1][g * CO_STRIDE + 16 + p]) : 0.0f;
        float s = a * a + b2 * b2;
        // 16-lane allreduce via row rotations (VALU latency, no LDS pipe)
        s += dppf<0x121>(s);   // row_ror:1
        s += dppf<0x122>(s);   // row_ror:2
        s += dppf<0x124>(s);   // row_ror:4
        s += dppf<0x128>(s);   // row_ror:8
        float rinv = 1.0f / sqrtf(s * (1.0f / 24.0f) + 1e-6f);
        float lr = lgp[0][g * CO_STRIDE + 8 + p] + lgp[1][g * CO_STRIDE + 8 + p];
        float yP = lr * rinv + bias[8 + p];
        float P = expf(s_ar[0] * yP);
        for (int it = 0; it < 20; ++it) {
            float r = P + dppf<0x39>(P);      // quad_perm [1,2,3,0]
            r += dppf<0x4E>(r);               // quad_perm [2,3,0,1]  -> row sum (axis -1)
            P *= __builtin_amdgcn_rcpf(r + 1e-6f);
            float c = P + dppf<0x124>(P);     // row_ror:4
            c += dppf<0x128>(c);              // row_ror:8            -> col sum (axis -2)
            P *= __builtin_amdgcn_rcpf(c + 1e-6f);
        }
        long tok = (long)blockIdx.x * 16 + g;
        cbuf[tok * 24 + 8 + p] = P;
        if (p < 8) {
            float yh = a * rinv + bias[p];
            float h = (p < 4) ? 1.0f / (1.0f + expf(-s_ap[0] * yh))
                              : 2.0f / (1.0f + expf(-s_apo[0] * yh));
            cbuf[tok * 24 + p] = h;
        }
    }
}

// ================= kernel 2: apply =================
// 16 tokens/block. x read straight from global (L3-hot after mhc_coef).
// LDS = 8.25KB(xin) + 1.5KB(coef) -> wave-limited 8 blocks/CU.
#define XIN_STRIDE 264   // 256 + 8 bf16 pad (528B = 33*16)

__global__ __launch_bounds__(256) void mhc_apply(
    const float* __restrict__ x, const float* __restrict__ cbuf,
    const unsigned short* __restrict__ WF, float* __restrict__ out)
{
    __shared__ unsigned short xin[16 * XIN_STRIDE]; // x_in tile, bf16
    __shared__ float coef[16 * 24];                 // [hpre0..3, hpost0..3, P[16]] per token

    const int t = threadIdx.x;
    const int lane = t & 63;
    const int w = t >> 6;
    const int quad = lane >> 4;
    const int col = lane & 15;
    const long base = (long)blockIdx.x * (16 * 1024);

    // ---- load coefficients (384 floats) ----
    {
        const float* cg = cbuf + (long)blockIdx.x * 384;
        coef[t] = cg[t];
        if (t < 128) coef[256 + t] = cg[256 + t];
    }
    __syncthreads();

    // ---- phase 3: x_in[tok][c] = sum_i hpre[i] * x[tok][i][c], c = t (f32 from global) ----
    {
        const float* xb = x + base + t;
        #pragma unroll 4
        for (int tok = 0; tok < 16; ++tok) {
            float4 h4 = *reinterpret_cast<const float4*>(&coef[tok * 24]);
            const float* xr = xb + tok * 1024;
            float s = h4.x * xr[0] + h4.y * xr[256] + h4.z * xr[512] + h4.w * xr[768];
            xin[tok * XIN_STRIDE + t] = f2bf(s);
        }
    }
    __syncthreads();

    // ---- phase 4: f_out = Xin(16x256) @ W^T, wave w does ntiles 4w..4w+3 ----
    short8 afr[8];
    #pragma unroll
    for (int ks = 0; ks < 8; ++ks)
        afr[ks] = *reinterpret_cast<const short8*>(&xin[col * XIN_STRIDE + ks * 32 + quad * 8]);
    floatx4 accs[4];
    #pragma unroll
    for (int nt = 0; nt < 4; ++nt) {
        floatx4 acc = {0.0f, 0.0f, 0.0f, 0.0f};
        int ntile = w * 4 + nt;
        #pragma unroll
        for (int ks = 0; ks < 8; ++ks) {
            short8 b = *reinterpret_cast<const short8*>(&WF[(ntile * 8 + ks) * 512 + lane * 8]);
            acc = __builtin_amdgcn_mfma_f32_16x16x32_bf16(afr[ks], b, acc, 0, 0, 0);
        }
        accs[nt] = acc;
    }

    // ---- phase 5: out[tok][o][c] = sum_i P[o][i] x[tok][i][c] + hpost[o]*f (f32 x) ----
    #pragma unroll
    for (int r = 0; r < 4; ++r) {
        int tok = quad * 4 + r;
        const float* cb = &coef[tok * 24];
        float4 hpo = *reinterpret_cast<const float4*>(cb + 4);
        float4 P0  = *reinterpret_cast<const float4*>(cb + 8);
        float4 P1  = *reinterpret_cast<const float4*>(cb + 12);
        float4 P2  = *reinterpret_cast<const float4*>(cb + 16);
        float4 P3  = *reinterpret_cast<const float4*>(cb + 20);
        long ob = base + (long)tok * 1024;
        const float* xr0 = x + ob;
        #pragma unroll
        for (int nt = 0; nt < 4; ++nt) {
            int c = (w * 4 + nt) * 16 + col;
            float f = accs[nt][r];
            float x0 = xr0[c],       x1 = xr0[256 + c];
            float x2 = xr0[512 + c], x3 = xr0[768 + c];
            out[ob + c]       = P0.x * x0 + P0.y * x1 + P0.z * x2 + P0.w * x3 + hpo.x * f;
            out[ob + 256 + c] = P1.x * x0 + P1.y * x1 + P1.z * x2 + P1.w * x3 + hpo.y * f;
            out[ob + 512 + c] = P2.x * x0 + P2.y * x1 + P2.z * x2 + P2.w * x3 + hpo.z * f;
            out[ob + 768 + c] = P3.x * x0 + P3.y * x1 + P3.z * x2 + P3.w * x3 + hpo.w * f;
        }
    }
}

extern "C" void kernel_launch(void* const* d_in, const int* in_sizes, int n_in,
                              void* d_out, int out_size, void* d_ws, size_t ws_size,
                              hipStream_t stream) {
    const float* x    = (const float*)d_in[0];
    const float* phi  = (const float*)d_in[1];
    const float* bias = (const float*)d_in[2];
    const float* ap   = (const float*)d_in[3];
    const float* apo  = (const float*)d_in[4];
    const float* ar   = (const float*)d_in[5];
    const float* W    = (const float*)d_in[6];
    float* out = (float*)d_out;

    unsigned short* phiF = (unsigned short*)d_ws;           // 32768 bf16
    unsigned short* WF   = (unsigned short*)d_ws + 32768;   // 65536 bf16
    float* cbuf = (float*)((char*)d_ws + 196608);           // 32768 tokens x 24 f32 = 3 MB

    mhc_prep<<<384, 256, 0, stream>>>(phi, W, phiF, WF);
    mhc_coef<<<2048, 256, 0, stream>>>(x, bias, ap, apo, ar, phiF, cbuf);
    mhc_apply<<<2048, 256, 0, stream>>>(x, cbuf, WF, out);
}

// Round 3
// 274.401 us; speedup vs baseline: 1.1994x; 1.0359x over previous
//
#include <hip/hip_runtime.h>

typedef __attribute__((ext_vector_type(4))) float floatx4;
typedef __attribute__((ext_vector_type(8))) short short8;

__device__ __forceinline__ unsigned short f2bf(float f) {
    union { float f; unsigned int i; } v; v.f = f;
    unsigned int x = v.i;
    unsigned int r = (x + 0x7FFFu + ((x >> 16) & 1u)) >> 16;   // RNE
    return (unsigned short)r;
}

// packed f32x2 -> bf16x2 (RNE), hw convert: low16 = cvt(lo), high16 = cvt(hi)
__device__ __forceinline__ unsigned int cvtpk_bf16(float lo, float hi) {
    unsigned int r;
    asm("v_cvt_pk_bf16_f32 %0, %1, %2" : "=v"(r) : "v"(lo), "v"(hi));
    return r;
}

// DPP lane-permute helper (VALU-latency cross-lane, no LDS pipe).
// ctrl: 0x00-0xFF quad_perm, 0x120+N row_ror:N (within 16-lane rows).
template<int CTRL>
__device__ __forceinline__ float dppf(float x) {
    return __int_as_float(__builtin_amdgcn_update_dpp(
        0, __float_as_int(x), CTRL, 0xF, 0xF, false));
}

// ---------------- prep: rearrange phi (1024x24) and W (256x256) into bf16
// MFMA B-fragment order in workspace.
// phiF: [kstep 0..31][ntile 0..1][lane 0..63][j 0..7]  (32768 bf16 = 64KB)
// WF  : [ntile 0..15][kstep 0..7][lane 0..63][j 0..7]  (65536 bf16 = 128KB)
// B-fragment: lane holds B[k = (lane>>4)*8 + j][n = lane&15]; B[k][n] = W[n][k] / phi[k][n]
__global__ void mhc_prep(const float* __restrict__ phi, const float* __restrict__ W,
                         unsigned short* __restrict__ phiF, unsigned short* __restrict__ WF) {
    int e = blockIdx.x * 256 + threadIdx.x;
    if (e < 32768) {
        int j = e & 7, lane = (e >> 3) & 63, nt = (e >> 9) & 1, ks = e >> 10;
        int n = nt * 16 + (lane & 15);
        int k = ks * 32 + ((lane >> 4) & 3) * 8 + j;
        float v = (n < 24) ? phi[k * 24 + n] : 0.0f;
        phiF[e] = f2bf(v);
    } else {
        int e2 = e - 32768;
        int j = e2 & 7, lane = (e2 >> 3) & 63, ks = (e2 >> 9) & 7, nt = e2 >> 12;
        int n = nt * 16 + (lane & 15);
        int k = ks * 32 + ((lane >> 4) & 3) * 8 + j;
        WF[e2] = f2bf(W[n * 256 + k]);
    }
}

// ================= fused main kernel, 8 tokens/block =================
// LDS = 16.5K(xs, reused as f32 fbuf) + 4.2K(xin) + 1.8K(lgp) + 0.8K(coef)
//     = 23.3 KB -> 7 blocks/CU (28 waves, 87% occupancy). VGPR capped at 73.
// Phases 3/5 read x as f32 straight from global (L2/L3-hot after phase 0);
// this frees xs after phase 1 so its space holds f_out in f32.
#define TOK 8
#define XS_STRIDE 1032   // bf16; 2064B rows (129*16: aligned, banks spread)
#define XIN_STRIDE 264   // bf16; 528B rows (33*16)
#define CO_STRIDE 28     // floats (lgp row)
#define F_STRIDE 260     // floats; 1040B rows (65*16)

__global__ __launch_bounds__(256, 7) void mhc_main(
    const float* __restrict__ x, const float* __restrict__ bias,
    const float* __restrict__ s_ap, const float* __restrict__ s_apo,
    const float* __restrict__ s_ar,
    const unsigned short* __restrict__ phiF, const unsigned short* __restrict__ WF,
    float* __restrict__ out)
{
    __shared__ alignas(16) unsigned short xs[TOK * XS_STRIDE];  // x bf16; -> f32 fbuf after ph1
    __shared__ alignas(16) unsigned short xin[TOK * XIN_STRIDE];
    __shared__ alignas(16) float lgp[2][TOK * CO_STRIDE];       // split-K logit partials
    __shared__ alignas(16) float coef[TOK * 24];                // [hpre0..3,hpost0..3,P[16]]
    float* fbuf = reinterpret_cast<float*>(xs);                 // [TOK][F_STRIDE] f32

    const int t = threadIdx.x;
    const int lane = t & 63;
    const int w = t >> 6;
    const int quad = lane >> 4;
    const int col = lane & 15;
    const long base = (long)blockIdx.x * (TOK * 1024);

    // ---- phase 0: global f32 -> bf16 LDS (one token row per ii) ----
    {
        const float4* xg = (const float4*)(x + base);
        #pragma unroll
        for (int ii = 0; ii < TOK; ++ii) {
            float4 v = xg[ii * 256 + t];
            uint2 pk;
            pk.x = cvtpk_bf16(v.x, v.y);
            pk.y = cvtpk_bf16(v.z, v.w);
            *reinterpret_cast<uint2*>(&xs[ii * XS_STRIDE + t * 4]) = pk;
        }
    }
    __syncthreads();

    // ---- phase 1: logits = V(8x1024) @ phi(1024x24), split-K over 4 waves ----
    // wave w: ntile = w&1, k-half = w>>1 (16 of 32 k-steps each). Rows 8-15 dup of 0-7.
    {
        floatx4 acc = {0.0f, 0.0f, 0.0f, 0.0f};
        const int ntile = w & 1;
        const int kh = w >> 1;
        const int arow = col & 7;
        for (int ks = kh * 16; ks < kh * 16 + 16; ++ks) {
            short8 a = *reinterpret_cast<const short8*>(&xs[arow * XS_STRIDE + ks * 32 + quad * 8]);
            short8 b = *reinterpret_cast<const short8*>(&phiF[(ks * 2 + ntile) * 512 + lane * 8]);
            acc = __builtin_amdgcn_mfma_f32_16x16x32_bf16(a, b, acc, 0, 0, 0);
        }
        int n = ntile * 16 + col;
        if (n < 24 && quad < 2) {
            #pragma unroll
            for (int r = 0; r < 4; ++r)
                lgp[kh][(quad * 4 + r) * CO_STRIDE + n] = acc[r];
        }
    }
    __syncthreads();

    // ---- phase 2: rms-norm, sigmoids, Sinkhorn (16 lanes/token, DPP; waves 0-1) ----
    if (t < 128) {
        int g = t >> 4, p = t & 15;
        float a  = lgp[0][g * CO_STRIDE + p]      + lgp[1][g * CO_STRIDE + p];
        float b2 = (p < 8) ? (lgp[0][g * CO_STRIDE + 16 + p] + lgp[1][g * CO_STRIDE + 16 + p]) : 0.0f;
        float s = a * a + b2 * b2;
        s += dppf<0x121>(s);   // row_ror:1
        s += dppf<0x122>(s);   // row_ror:2
        s += dppf<0x124>(s);   // row_ror:4
        s += dppf<0x128>(s);   // row_ror:8   -> 16-lane allreduce
        float rinv = 1.0f / sqrtf(s * (1.0f / 24.0f) + 1e-6f);
        float lr = lgp[0][g * CO_STRIDE + 8 + p] + lgp[1][g * CO_STRIDE + 8 + p];
        float yP = lr * rinv + bias[8 + p];
        float P = expf(s_ar[0] * yP);
        for (int it = 0; it < 20; ++it) {
            float r = P + dppf<0x39>(P);      // quad_perm [1,2,3,0]
            r += dppf<0x4E>(r);               // quad_perm [2,3,0,1]  -> row sum (axis -1)
            P *= __builtin_amdgcn_rcpf(r + 1e-6f);
            float c = P + dppf<0x124>(P);     // row_ror:4
            c += dppf<0x128>(c);              // row_ror:8            -> col sum (axis -2)
            P *= __builtin_amdgcn_rcpf(c + 1e-6f);
        }
        coef[g * 24 + 8 + p] = P;
        if (p < 8) {
            float yh = a * rinv + bias[p];
            float h = (p < 4) ? 1.0f / (1.0f + expf(-s_ap[0] * yh))
                              : 2.0f / (1.0f + expf(-s_apo[0] * yh));
            coef[g * 24 + p] = h;
        }
    }
    __syncthreads();

    // ---- phase 3: x_in[tok][c] = sum_i hpre[i]*x[tok][i][c], f32 x from global ----
    // thread: 4 consecutive c (float4), wave w handles tokens 2w, 2w+1
    {
        const int cc = (t & 63) * 4;
        const int tok0 = w * 2;
        #pragma unroll
        for (int s = 0; s < 2; ++s) {
            int tok = tok0 + s;
            float4 h4 = *reinterpret_cast<const float4*>(&coef[tok * 24]);
            const float* xr = x + base + tok * 1024 + cc;
            float4 x0 = *reinterpret_cast<const float4*>(xr);
            float4 x1 = *reinterpret_cast<const float4*>(xr + 256);
            float4 x2 = *reinterpret_cast<const float4*>(xr + 512);
            float4 x3 = *reinterpret_cast<const float4*>(xr + 768);
            float4 sr;
            sr.x = h4.x * x0.x + h4.y * x1.x + h4.z * x2.x + h4.w * x3.x;
            sr.y = h4.x * x0.y + h4.y * x1.y + h4.z * x2.y + h4.w * x3.y;
            sr.z = h4.x * x0.z + h4.y * x1.z + h4.z * x2.z + h4.w * x3.z;
            sr.w = h4.x * x0.w + h4.y * x1.w + h4.z * x2.w + h4.w * x3.w;
            uint2 pk;
            pk.x = cvtpk_bf16(sr.x, sr.y);
            pk.y = cvtpk_bf16(sr.z, sr.w);
            *reinterpret_cast<uint2*>(&xin[tok * XIN_STRIDE + cc]) = pk;
        }
    }
    __syncthreads();

    // ---- phase 4: f_out = Xin(8x256) @ W^T; wave w does ntiles 4w..4w+3 ----
    {
        const int arow = col & 7;
        short8 afr[8];
        #pragma unroll
        for (int ks = 0; ks < 8; ++ks)
            afr[ks] = *reinterpret_cast<const short8*>(&xin[arow * XIN_STRIDE + ks * 32 + quad * 8]);
        floatx4 accs[4];
        #pragma unroll
        for (int nt = 0; nt < 4; ++nt) {
            floatx4 acc = {0.0f, 0.0f, 0.0f, 0.0f};
            int ntile = w * 4 + nt;
            #pragma unroll
            for (int ks = 0; ks < 8; ++ks) {
                short8 b = *reinterpret_cast<const short8*>(&WF[(ntile * 8 + ks) * 512 + lane * 8]);
                acc = __builtin_amdgcn_mfma_f32_16x16x32_bf16(afr[ks], b, acc, 0, 0, 0);
            }
            accs[nt] = acc;
        }
        // write f32 f_out into the (now dead) xs region; valid rows live on quads 0-1
        if (quad < 2) {
            #pragma unroll
            for (int nt = 0; nt < 4; ++nt) {
                int n = (w * 4 + nt) * 16 + col;
                #pragma unroll
                for (int r = 0; r < 4; ++r)
                    fbuf[(quad * 4 + r) * F_STRIDE + n] = accs[nt][r];
            }
        }
    }
    __syncthreads();

    // ---- phase 5: out[tok][o][c] = sum_i P[o][i]*x[tok][i][c] + hpost[o]*f[c] ----
    {
        const int cc = (t & 63) * 4;
        const int tok0 = w * 2;
        #pragma unroll
        for (int s = 0; s < 2; ++s) {
            int tok = tok0 + s;
            const float* cb = &coef[tok * 24];
            float4 hpo = *reinterpret_cast<const float4*>(cb + 4);
            float4 P0  = *reinterpret_cast<const float4*>(cb + 8);
            float4 P1  = *reinterpret_cast<const float4*>(cb + 12);
            float4 P2  = *reinterpret_cast<const float4*>(cb + 16);
            float4 P3  = *reinterpret_cast<const float4*>(cb + 20);
            const float* xr = x + base + tok * 1024 + cc;
            float4 x0 = *reinterpret_cast<const float4*>(xr);
            float4 x1 = *reinterpret_cast<const float4*>(xr + 256);
            float4 x2 = *reinterpret_cast<const float4*>(xr + 512);
            float4 x3 = *reinterpret_cast<const float4*>(xr + 768);
            float4 f  = *reinterpret_cast<const float4*>(&fbuf[tok * F_STRIDE + cc]);
            float* ob = out + base + tok * 1024 + cc;
            float4 o0, o1, o2, o3;
            o0.x = P0.x*x0.x + P0.y*x1.x + P0.z*x2.x + P0.w*x3.x + hpo.x*f.x;
            o0.y = P0.x*x0.y + P0.y*x1.y + P0.z*x2.y + P0.w*x3.y + hpo.x*f.y;
            o0.z = P0.x*x0.z + P0.y*x1.z + P0.z*x2.z + P0.w*x3.z + hpo.x*f.z;
            o0.w = P0.x*x0.w + P0.y*x1.w + P0.z*x2.w + P0.w*x3.w + hpo.x*f.w;
            o1.x = P1.x*x0.x + P1.y*x1.x + P1.z*x2.x + P1.w*x3.x + hpo.y*f.x;
            o1.y = P1.x*x0.y + P1.y*x1.y + P1.z*x2.y + P1.w*x3.y + hpo.y*f.y;
            o1.z = P1.x*x0.z + P1.y*x1.z + P1.z*x2.z + P1.w*x3.z + hpo.y*f.z;
            o1.w = P1.x*x0.w + P1.y*x1.w + P1.z*x2.w + P1.w*x3.w + hpo.y*f.w;
            o2.x = P2.x*x0.x + P2.y*x1.x + P2.z*x2.x + P2.w*x3.x + hpo.z*f.x;
            o2.y = P2.x*x0.y + P2.y*x1.y + P2.z*x2.y + P2.w*x3.y + hpo.z*f.y;
            o2.z = P2.x*x0.z + P2.y*x1.z + P2.z*x2.z + P2.w*x3.z + hpo.z*f.z;
            o2.w = P2.x*x0.w + P2.y*x1.w + P2.z*x2.w + P2.w*x3.w + hpo.z*f.w;
            o3.x = P3.x*x0.x + P3.y*x1.x + P3.z*x2.x + P3.w*x3.x + hpo.w*f.x;
            o3.y = P3.x*x0.y + P3.y*x1.y + P3.z*x2.y + P3.w*x3.y + hpo.w*f.y;
            o3.z = P3.x*x0.z + P3.y*x1.z + P3.z*x2.z + P3.w*x3.z + hpo.w*f.z;
            o3.w = P3.x*x0.w + P3.y*x1.w + P3.z*x2.w + P3.w*x3.w + hpo.w*f.w;
            *reinterpret_cast<float4*>(ob)       = o0;
            *reinterpret_cast<float4*>(ob + 256) = o1;
            *reinterpret_cast<float4*>(ob + 512) = o2;
            *reinterpret_cast<float4*>(ob + 768) = o3;
        }
    }
}

extern "C" void kernel_launch(void* const* d_in, const int* in_sizes, int n_in,
                              void* d_out, int out_size, void* d_ws, size_t ws_size,
                              hipStream_t stream) {
    const float* x    = (const float*)d_in[0];
    const float* phi  = (const float*)d_in[1];
    const float* bias = (const float*)d_in[2];
    const float* ap   = (const float*)d_in[3];
    const float* apo  = (const float*)d_in[4];
    const float* ar   = (const float*)d_in[5];
    const float* W    = (const float*)d_in[6];
    float* out = (float*)d_out;

    unsigned short* phiF = (unsigned short*)d_ws;           // 32768 bf16
    unsigned short* WF   = (unsigned short*)d_ws + 32768;   // 65536 bf16

    mhc_prep<<<384, 256, 0, stream>>>(phi, W, phiF, WF);
    mhc_main<<<4096, 256, 0, stream>>>(x, bias, ap, apo, ar, phiF, WF, out);
}

// Round 4
// 262.111 us; speedup vs baseline: 1.2556x; 1.0469x over previous
//
#include <hip/hip_runtime.h>

typedef __attribute__((ext_vector_type(4))) float floatx4;
typedef __attribute__((ext_vector_type(8))) short short8;

__device__ __forceinline__ unsigned short f2bf(float f) {
    union { float f; unsigned int i; } v; v.f = f;
    unsigned int x = v.i;
    unsigned int r = (x + 0x7FFFu + ((x >> 16) & 1u)) >> 16;   // RNE
    return (unsigned short)r;
}
__device__ __forceinline__ float bf2f(unsigned short u) {
    union { unsigned int i; float f; } v; v.i = ((unsigned int)u) << 16;
    return v.f;
}

// packed f32x2 -> bf16x2 (RNE), hw convert: low16 = cvt(lo), high16 = cvt(hi)
__device__ __forceinline__ unsigned int cvtpk_bf16(float lo, float hi) {
    unsigned int r;
    asm("v_cvt_pk_bf16_f32 %0, %1, %2" : "=v"(r) : "v"(lo), "v"(hi));
    return r;
}

// DPP lane-permute helper (VALU-latency cross-lane, no LDS pipe).
template<int CTRL>
__device__ __forceinline__ float dppf(float x) {
    return __int_as_float(__builtin_amdgcn_update_dpp(
        0, __float_as_int(x), CTRL, 0xF, 0xF, false));
}

// ---------------- prep: rearrange phi (1024x24) and W (256x256) into bf16
// MFMA B-fragment order in workspace.
// phiF: [kstep 0..31][ntile 0..1][lane 0..63][j 0..7]  (32768 bf16 = 64KB)
// WF  : [ntile 0..15][kstep 0..7][lane 0..63][j 0..7]  (65536 bf16 = 128KB)
// B-fragment: lane holds B[k = (lane>>4)*8 + j][n = lane&15]; B[k][n] = W[n][k] / phi[k][n]
__global__ void mhc_prep(const float* __restrict__ phi, const float* __restrict__ W,
                         unsigned short* __restrict__ phiF, unsigned short* __restrict__ WF) {
    int e = blockIdx.x * 256 + threadIdx.x;
    if (e < 32768) {
        int j = e & 7, lane = (e >> 3) & 63, nt = (e >> 9) & 1, ks = e >> 10;
        int n = nt * 16 + (lane & 15);
        int k = ks * 32 + ((lane >> 4) & 3) * 8 + j;
        float v = (n < 24) ? phi[k * 24 + n] : 0.0f;
        phiF[e] = f2bf(v);
    } else {
        int e2 = e - 32768;
        int j = e2 & 7, lane = (e2 >> 3) & 63, ks = (e2 >> 9) & 7, nt = e2 >> 12;
        int n = nt * 16 + (lane & 15);
        int k = ks * 32 + ((lane >> 4) & 3) * 8 + j;
        WF[e2] = f2bf(W[n * 256 + k]);
    }
}

// ================= fused main kernel, 8 tokens/block =================
// Combine R0's single-pass traffic (x lives in bf16 LDS through phase 5) with
// R3's occupancy (small tile): LDS = 16.5K(xs) + 4.2K(xin, aliases lgp) +
// 0.8K(coef) = 21.0 KB -> 7 blocks/CU (28 waves). VGPR capped at 73 via
// __launch_bounds__(256,7); R0's identical phase structure used 68.
#define TOK 8
#define XS_STRIDE 1032   // bf16; 2064B rows (129*16: aligned, banks spread)
#define XIN_STRIDE 264   // bf16; 528B rows (33*16)
#define CO_STRIDE 28     // floats (lgp row)

__global__ __launch_bounds__(256, 7) void mhc_main(
    const float* __restrict__ x, const float* __restrict__ bias,
    const float* __restrict__ s_ap, const float* __restrict__ s_apo,
    const float* __restrict__ s_ar,
    const unsigned short* __restrict__ phiF, const unsigned short* __restrict__ WF,
    float* __restrict__ out)
{
    __shared__ alignas(16) unsigned short xs[TOK * XS_STRIDE];      // x bf16, live all phases
    __shared__ alignas(16) unsigned short xin_u[TOK * XIN_STRIDE];  // xin (ph3+); lgp (ph1-2)
    __shared__ alignas(16) float coef[TOK * 24];                    // [hpre0..3,hpost0..3,P[16]]
    float* lgp = reinterpret_cast<float*>(xin_u);                   // [2][TOK*CO_STRIDE] = 1792B

    const int t = threadIdx.x;
    const int lane = t & 63;
    const int w = t >> 6;
    const int quad = lane >> 4;
    const int col = lane & 15;
    const long base = (long)blockIdx.x * (TOK * 1024);

    // ---- phase 0: global f32 -> bf16 LDS (one token row per ii) ----
    {
        const float4* xg = (const float4*)(x + base);
        #pragma unroll
        for (int ii = 0; ii < TOK; ++ii) {
            float4 v = xg[ii * 256 + t];
            uint2 pk;
            pk.x = cvtpk_bf16(v.x, v.y);
            pk.y = cvtpk_bf16(v.z, v.w);
            *reinterpret_cast<uint2*>(&xs[ii * XS_STRIDE + t * 4]) = pk;
        }
    }
    __syncthreads();

    // ---- phase 1: logits = V(8x1024) @ phi(1024x24), split-K over 4 waves ----
    // wave w: ntile = w&1, k-half = w>>1. A rows 8-15 duplicate rows 0-7.
    {
        floatx4 acc = {0.0f, 0.0f, 0.0f, 0.0f};
        const int ntile = w & 1;
        const int kh = w >> 1;
        const int arow = col & 7;
        for (int ks = kh * 16; ks < kh * 16 + 16; ++ks) {
            short8 a = *reinterpret_cast<const short8*>(&xs[arow * XS_STRIDE + ks * 32 + quad * 8]);
            short8 b = *reinterpret_cast<const short8*>(&phiF[(ks * 2 + ntile) * 512 + lane * 8]);
            acc = __builtin_amdgcn_mfma_f32_16x16x32_bf16(a, b, acc, 0, 0, 0);
        }
        int n = ntile * 16 + col;
        if (n < 24 && quad < 2) {
            #pragma unroll
            for (int r = 0; r < 4; ++r)
                lgp[kh * (TOK * CO_STRIDE) + (quad * 4 + r) * CO_STRIDE + n] = acc[r];
        }
    }
    __syncthreads();

    // ---- phase 2: rms-norm, sigmoids, Sinkhorn (16 lanes/token, DPP; waves 0-1) ----
    if (t < 128) {
        int g = t >> 4, p = t & 15;
        const float* l0 = lgp + g * CO_STRIDE;
        const float* l1 = lgp + TOK * CO_STRIDE + g * CO_STRIDE;
        float a  = l0[p] + l1[p];
        float b2 = (p < 8) ? (l0[16 + p] + l1[16 + p]) : 0.0f;
        float s = a * a + b2 * b2;
        s += dppf<0x121>(s);   // row_ror:1
        s += dppf<0x122>(s);   // row_ror:2
        s += dppf<0x124>(s);   // row_ror:4
        s += dppf<0x128>(s);   // row_ror:8   -> 16-lane allreduce
        float rinv = 1.0f / sqrtf(s * (1.0f / 24.0f) + 1e-6f);
        float yP = (l0[8 + p] + l1[8 + p]) * rinv + bias[8 + p];
        float P = expf(s_ar[0] * yP);
        for (int it = 0; it < 20; ++it) {
            float r = P + dppf<0x39>(P);      // quad_perm [1,2,3,0]
            r += dppf<0x4E>(r);               // quad_perm [2,3,0,1]  -> row sum (axis -1)
            P *= __builtin_amdgcn_rcpf(r + 1e-6f);
            float c = P + dppf<0x124>(P);     // row_ror:4
            c += dppf<0x128>(c);              // row_ror:8            -> col sum (axis -2)
            P *= __builtin_amdgcn_rcpf(c + 1e-6f);
        }
        coef[g * 24 + 8 + p] = P;
        if (p < 8) {
            float yh = a * rinv + bias[p];
            float h = (p < 4) ? 1.0f / (1.0f + expf(-s_ap[0] * yh))
                              : 2.0f / (1.0f + expf(-s_apo[0] * yh));
            coef[g * 24 + p] = h;
        }
    }
    __syncthreads();   // also fences lgp before xin overwrites it

    // ---- phase 3: x_in[tok][c] = sum_i hpre[i]*x[tok][i][c], bf16 x from LDS ----
    {
        const int c = t;
        #pragma unroll
        for (int tok = 0; tok < TOK; ++tok) {
            float4 h4 = *reinterpret_cast<const float4*>(&coef[tok * 24]);
            const unsigned short* xr = &xs[tok * XS_STRIDE + c];
            float sv = h4.x * bf2f(xr[0]) + h4.y * bf2f(xr[256])
                     + h4.z * bf2f(xr[512]) + h4.w * bf2f(xr[768]);
            xin_u[tok * XIN_STRIDE + c] = f2bf(sv);
        }
    }
    __syncthreads();

    // ---- phase 4: f_out = Xin(8x256) @ W^T; wave w does ntiles 4w..4w+3 ----
    floatx4 accs[4];
    {
        const int arow = col & 7;
        short8 afr[8];
        #pragma unroll
        for (int ks = 0; ks < 8; ++ks)
            afr[ks] = *reinterpret_cast<const short8*>(&xin_u[arow * XIN_STRIDE + ks * 32 + quad * 8]);
        #pragma unroll
        for (int nt = 0; nt < 4; ++nt) {
            floatx4 acc = {0.0f, 0.0f, 0.0f, 0.0f};
            int ntile = w * 4 + nt;
            #pragma unroll
            for (int ks = 0; ks < 8; ++ks) {
                short8 b = *reinterpret_cast<const short8*>(&WF[(ntile * 8 + ks) * 512 + lane * 8]);
                acc = __builtin_amdgcn_mfma_f32_16x16x32_bf16(afr[ks], b, acc, 0, 0, 0);
            }
            accs[nt] = acc;
        }
    }
    // no barrier needed: phase 5 uses accs (registers), xs, coef — all stable

    // ---- phase 5: out[tok][o][c] = sum_i P[o][i]*x[tok][i][c] + hpost[o]*f[c] ----
    // D rows 8-15 duplicate toks 0-7: quads {0,2} hold toks 0-3, {1,3} toks 4-7.
    // o-head split: quads 0-1 store o=0,1; quads 2-3 store o=2,3. All lanes busy.
    {
        const int o0 = (quad >> 1) * 2;          // 0 or 2
        #pragma unroll
        for (int r = 0; r < 4; ++r) {
            int tok = (quad & 1) * 4 + r;
            const float* cb = &coef[tok * 24];
            float hpoA = cb[4 + o0], hpoB = cb[5 + o0];
            float4 PA = *reinterpret_cast<const float4*>(cb + 8 + 4 * o0);
            float4 PB = *reinterpret_cast<const float4*>(cb + 12 + 4 * o0);
            long ob = base + (long)tok * 1024 + (long)o0 * 256;
            #pragma unroll
            for (int nt = 0; nt < 4; ++nt) {
                int c = (w * 4 + nt) * 16 + col;
                float f = accs[nt][r];
                const unsigned short* xr = &xs[tok * XS_STRIDE + c];
                float x0 = bf2f(xr[0]),   x1 = bf2f(xr[256]);
                float x2 = bf2f(xr[512]), x3 = bf2f(xr[768]);
                out[ob + c]       = PA.x * x0 + PA.y * x1 + PA.z * x2 + PA.w * x3 + hpoA * f;
                out[ob + 256 + c] = PB.x * x0 + PB.y * x1 + PB.z * x2 + PB.w * x3 + hpoB * f;
            }
        }
    }
}

extern "C" void kernel_launch(void* const* d_in, const int* in_sizes, int n_in,
                              void* d_out, int out_size, void* d_ws, size_t ws_size,
                              hipStream_t stream) {
    const float* x    = (const float*)d_in[0];
    const float* phi  = (const float*)d_in[1];
    const float* bias = (const float*)d_in[2];
    const float* ap   = (const float*)d_in[3];
    const float* apo  = (const float*)d_in[4];
    const float* ar   = (const float*)d_in[5];
    const float* W    = (const float*)d_in[6];
    float* out = (float*)d_out;

    unsigned short* phiF = (unsigned short*)d_ws;           // 32768 bf16
    unsigned short* WF   = (unsigned short*)d_ws + 32768;   // 65536 bf16

    mhc_prep<<<384, 256, 0, stream>>>(phi, W, phiF, WF);
    mhc_main<<<4096, 256, 0, stream>>>(x, bias, ap, apo, ar, phiF, WF, out);
}